// Round 19
// baseline (582.699 us; speedup 1.0000x reference)
//
#include <hip/hip_runtime.h>

typedef short bf16x8 __attribute__((ext_vector_type(8)));
typedef float f32x4  __attribute__((ext_vector_type(4)));
typedef unsigned short u16;
typedef unsigned short u16x8 __attribute__((ext_vector_type(8)));

#define NB   32
#define NS   256
#define NV   32000
#define NE   128
#define NH   128
#define NR   8192   // NB*NS
#define NG   512    // 4*NH
#define NCHUNK 500  // 500 col chunks of 64

__device__ __forceinline__ float sigm(float x){
    return __builtin_amdgcn_rcpf(1.0f + __expf(-x));
}
__device__ __forceinline__ float tanh_fast(float x){
    return 1.0f - 2.0f*__builtin_amdgcn_rcpf(1.0f + __expf(2.0f*x));
}

__device__ __forceinline__ u16 f2bf(float x){
    unsigned u = __float_as_uint(x);
    unsigned r = (u + 0x7FFFu + ((u >> 16) & 1u)) >> 16;
    return (u16)r;
}

// raw barrier: waits only LDS ops, lets global loads/stores stay in flight
__device__ __forceinline__ void lds_barrier(){
    asm volatile("s_waitcnt lgkmcnt(0)" ::: "memory");
    __builtin_amdgcn_s_barrier();
    __builtin_amdgcn_sched_barrier(0);
}

// ---------------------------------------------------------------------------
// Fragment-major (F) layout for a [R][128] bf16 matrix, shared by A and B:
//   row m = rb*64 + q*16 + l15,  col j = kk*32 + l4*8 + e,  lane = l4*16+l15
//   F-addr = rb*8192 + (kk*4+q)*512 + lane*8 + e      (u16 units)
// ---------------------------------------------------------------------------

// hh[b][j] = b_ih[j] + b_hh[j] + dot(h0[b,:], W_hh[j,:])
__global__ __launch_bounds__(256) void khh(const float* __restrict__ h0,
                                           const float* __restrict__ W_hh,
                                           const float* __restrict__ b_ih,
                                           const float* __restrict__ b_hh,
                                           float* __restrict__ hh){
    int idx = blockIdx.x*256 + threadIdx.x;      // 0..16383
    int b = idx >> 9, j = idx & 511;
    const float4* h4 = (const float4*)(h0 + b*NH);
    const float4* w4 = (const float4*)(W_hh + j*NH);
    float acc = b_ih[j] + b_hh[j];
    #pragma unroll
    for (int k = 0; k < 32; ++k){
        float4 a = h4[k], w = w4[k];
        acc += a.x*w.x + a.y*w.y + a.z*w.z + a.w*w.w;
    }
    hh[idx] = acc;
}

// W_pred fp32 -> bf16, written directly in F layout
__global__ __launch_bounds__(256) void kwb(const float* __restrict__ src, u16* __restrict__ dst){
    int a8 = blockIdx.x*256 + threadIdx.x;    // 512000 16B-chunks
    int a = a8 * 8;
    int rb = a >> 13; int blk = (a >> 9) & 15; int lane = (a >> 3) & 63;
    int q = blk & 3, kk = blk >> 2;
    int l15 = lane & 15, l4 = lane >> 4;
    int m = rb*64 + q*16 + l15;
    int j = kk*32 + l4*8;
    const float* s = src + (size_t)m*NH + j;
    float4 x = *(const float4*)s, y = *(const float4*)(s + 4);
    u16x8 o;
    o[0]=f2bf(x.x); o[1]=f2bf(x.y); o[2]=f2bf(x.z); o[3]=f2bf(x.w);
    o[4]=f2bf(y.x); o[5]=f2bf(y.y); o[6]=f2bf(y.z); o[7]=f2bf(y.w);
    *(u16x8*)&dst[a] = o;
}

// hsb (row-major [8192][128] bf16) -> hsbF (F layout). 2 MB, L2-resident.
__global__ __launch_bounds__(256) void ktr(const u16* __restrict__ src, u16* __restrict__ dst){
    int a8 = blockIdx.x*256 + threadIdx.x;    // 262144 16B-chunks
    int a = a8 * 8;
    int rb = a >> 13; int blk = (a >> 9) & 15; int lane = (a >> 3) & 63;
    int q = blk & 3, kk = blk >> 2;
    int l15 = lane & 15, l4 = lane >> 4;
    int m = rb*64 + q*16 + l15;
    int j = kk*32 + l4*8;
    *(uint4*)&dst[a] = *(const uint4*)&src[(size_t)m*NH + j];
}

// xg[r][j] = dot(emb[seq[r]], W_ih[j][0:128]);  32 rows x 512 cols per block
// (32 rows halves the W_ih refetch vs 16: 268 MB -> 134 MB)
__global__ __launch_bounds__(256) void kxg(const int* __restrict__ seq,
                                           const float* __restrict__ emb,
                                           const float* __restrict__ W_ih,
                                           float* __restrict__ xg){
    __shared__ float4 xs[32][32];
    int m0 = blockIdx.x * 32;
    int t = threadIdx.x;
    int r = t >> 3, k8 = t & 7;
    int tok = seq[m0 + r];
    #pragma unroll
    for (int j = 0; j < 4; ++j)
        xs[r][k8*4 + j] = *(const float4*)(emb + (size_t)tok*NE + (k8*4 + j)*4);
    __syncthreads();
    int j0 = t, j1 = t + 256;
    const float4* w0 = (const float4*)(W_ih + (size_t)j0*256);
    const float4* w1 = (const float4*)(W_ih + (size_t)j1*256);
    float acc0[32], acc1[32];
    #pragma unroll
    for (int r2 = 0; r2 < 32; ++r2){ acc0[r2]=0.f; acc1[r2]=0.f; }
    #pragma unroll
    for (int k = 0; k < 32; ++k){
        float4 wa = w0[k], wb = w1[k];
        #pragma unroll
        for (int r2 = 0; r2 < 32; ++r2){
            float4 xv = xs[r2][k];
            acc0[r2] += xv.x*wa.x + xv.y*wa.y + xv.z*wa.z + xv.w*wa.w;
            acc1[r2] += xv.x*wb.x + xv.y*wb.y + xv.z*wb.z + xv.w*wb.w;
        }
    }
    #pragma unroll
    for (int r2 = 0; r2 < 32; ++r2){
        xg[(size_t)(m0+r2)*NG + j0] = acc0[r2];
        xg[(size_t)(m0+r2)*NG + j1] = acc1[r2];
    }
}

// ---------------------------------------------------------------------------
// Sequential LSTM v3: 512 threads/block, quarter-split dots (R18: neutral vs
// v2 -> latency-chain bound; kept as-is).
// ---------------------------------------------------------------------------
#define DOT16(ACC, B) {                                                         \
    asm("v_dot2_f32_bf16 %0, %1, %2, %0" : "+v"(ACC) : "v"(hq0.x), "v"(w2[(B)+0])); \
    asm("v_dot2_f32_bf16 %0, %1, %2, %0" : "+v"(ACC) : "v"(hq0.y), "v"(w2[(B)+1])); \
    asm("v_dot2_f32_bf16 %0, %1, %2, %0" : "+v"(ACC) : "v"(hq0.z), "v"(w2[(B)+2])); \
    asm("v_dot2_f32_bf16 %0, %1, %2, %0" : "+v"(ACC) : "v"(hq0.w), "v"(w2[(B)+3])); \
    asm("v_dot2_f32_bf16 %0, %1, %2, %0" : "+v"(ACC) : "v"(hq1.x), "v"(w2[(B)+4])); \
    asm("v_dot2_f32_bf16 %0, %1, %2, %0" : "+v"(ACC) : "v"(hq1.y), "v"(w2[(B)+5])); \
    asm("v_dot2_f32_bf16 %0, %1, %2, %0" : "+v"(ACC) : "v"(hq1.z), "v"(w2[(B)+6])); \
    asm("v_dot2_f32_bf16 %0, %1, %2, %0" : "+v"(ACC) : "v"(hq1.w), "v"(w2[(B)+7])); \
    asm("v_dot2_f32_bf16 %0, %1, %2, %0" : "+v"(ACC) : "v"(hq2.x), "v"(w2[(B)+8])); \
    asm("v_dot2_f32_bf16 %0, %1, %2, %0" : "+v"(ACC) : "v"(hq2.y), "v"(w2[(B)+9])); \
    asm("v_dot2_f32_bf16 %0, %1, %2, %0" : "+v"(ACC) : "v"(hq2.z), "v"(w2[(B)+10])); \
    asm("v_dot2_f32_bf16 %0, %1, %2, %0" : "+v"(ACC) : "v"(hq2.w), "v"(w2[(B)+11])); \
    asm("v_dot2_f32_bf16 %0, %1, %2, %0" : "+v"(ACC) : "v"(hq3.x), "v"(w2[(B)+12])); \
    asm("v_dot2_f32_bf16 %0, %1, %2, %0" : "+v"(ACC) : "v"(hq3.y), "v"(w2[(B)+13])); \
    asm("v_dot2_f32_bf16 %0, %1, %2, %0" : "+v"(ACC) : "v"(hq3.z), "v"(w2[(B)+14])); \
    asm("v_dot2_f32_bf16 %0, %1, %2, %0" : "+v"(ACC) : "v"(hq3.w), "v"(w2[(B)+15])); \
}

#define LSTM_STEP(S, XV) {                                                      \
    const uint4* h4 = (const uint4*)&hsh2[(S) & 1][0];                          \
    uint4 hq0 = h4[p4+0], hq1 = h4[p4+1], hq2 = h4[p4+2], hq3 = h4[p4+3];       \
    float s0=0.f, s1=0.f, s2=0.f, s3=0.f;                                       \
    DOT16(s0, 0); DOT16(s1, 16); DOT16(s2, 32); DOT16(s3, 48);                  \
    float hbx = hba + (XV);                                                     \
    s0 += (p == 0) ? hbx : 0.f;                                                 \
    s1 += (p == 1) ? hbx : 0.f;                                                 \
    s2 += (p == 2) ? hbx : 0.f;                                                 \
    s3 += (p == 3) ? hbx : 0.f;                                                 \
    s0 += __shfl_xor(s0, 1); s0 += __shfl_xor(s0, 2);                           \
    s1 += __shfl_xor(s1, 1); s1 += __shfl_xor(s1, 2);                           \
    s2 += __shfl_xor(s2, 1); s2 += __shfl_xor(s2, 2);                           \
    s3 += __shfl_xor(s3, 1); s3 += __shfl_xor(s3, 2);                           \
    float cc = sigm(s1)*c0r + sigm(s0)*tanh_fast(s2);                           \
    float h  = sigm(s3)*tanh_fast(cc);                                          \
    u16 hb16 = f2bf(h);                                                         \
    unsigned hp = __shfl_xor((unsigned)hb16, 4);   /* h of row r^1 */           \
    if ((t & 7) == 0){                                                          \
        unsigned pair = (hp << 16) | (unsigned)hb16;                            \
        hsh2[((S) & 1) ^ 1][r >> 1] = pair;                                     \
        *(unsigned*)&hrow[(S)*NH + r] = pair;                                   \
    }                                                                           \
    lds_barrier();                                                              \
}

__global__ __launch_bounds__(512, 1) void klstm(const float* __restrict__ xg,
                                                const float* __restrict__ hh,
                                                const float* __restrict__ W_ih,
                                                const float* __restrict__ c0,
                                                u16* __restrict__ hs){
    __shared__ __align__(16) unsigned hsh2[2][64];   // h as 64 packed bf16 pairs, x2 buffers
    int b = blockIdx.x, t = threadIdx.x;
    int r = t >> 2;          // hidden row 0..127
    int p = t & 3;           // h-quarter == owned gate type (0=i,1=f,2=g,3=o)
    int p4 = p * 4;
    unsigned w2[64];
    #pragma unroll
    for (int j = 0; j < 4; ++j){
        const float2* wrj = (const float2*)(W_ih + (size_t)(j*NH + r)*256 + 128 + p*32);
        #pragma unroll
        for (int k = 0; k < 16; ++k){
            float2 v = wrj[k];
            w2[j*16 + k] = ((unsigned)f2bf(v.y) << 16) | (unsigned)f2bf(v.x);
        }
    }
    float hba = hh[b*NG + p*NH + r];     // bias+enc term for own gate
    float c0r = c0[b*NH + r];
    if (t < 64){ hsh2[0][t] = 0u; }      // h_init = 0
    __syncthreads();
    const float* xrow = xg + (size_t)b*NS*NG + p*NH + r;   // own gate's x, stride NG
    u16* hrow = hs + (size_t)b*NS*NH;
    float xv0 = xrow[0], xv1 = xrow[NG], xv2 = xrow[2*NG], xv3 = xrow[3*NG];
    for (int s4 = 0; s4 < NS; s4 += 4){
        float n0=0.f, n1=0.f, n2=0.f, n3=0.f;
        if (s4 + 4 < NS){
            const float* xn = xrow + (size_t)(s4+4)*NG;
            n0 = xn[0]; n1 = xn[NG]; n2 = xn[2*NG]; n3 = xn[3*NG];
        }
        LSTM_STEP(s4+0, xv0);
        LSTM_STEP(s4+1, xv1);
        LSTM_STEP(s4+2, xv2);
        LSTM_STEP(s4+3, xv3);
        xv0=n0; xv1=n1; xv2=n2; xv3=n3;
    }
}

// ---------------------------------------------------------------------------
// A-persistent MFMA GEMM (R18 diagnosis: per-tile A-fragment reloads with
// 2-4x wave redundancy = ~2 GB L2 traffic/pass -> load-bound, MfmaUtil low).
// Grid 1600 = 32 row-groups x 50 col-groups. Block = 4 waves x 64 DISTINCT
// rows (af loaded ONCE, 64 VGPR) x 10 col chunks of 64 (bfr streamed, 64
// VGPR, reloaded after each chunk's MFMA). Read traffic/pass ~0.36 GB.
// PASS 0: psum[ch][row] = sum_j exp(logit) (coalesced per-wave store).
// PASS 1: out = logit - lse[row] (lse loaded once per block).
// ---------------------------------------------------------------------------

#define LOAD_B(CH) {                                                            \
    const u16* pb = wbF + (size_t)(CH)*8192 + lane*8;                           \
    _Pragma("unroll")                                                           \
    for (int f = 0; f < 4; ++f)                                                 \
        _Pragma("unroll")                                                       \
        for (int kk = 0; kk < 4; ++kk)                                          \
            bfr[f][kk] = *(const bf16x8*)&pb[(kk*4 + f)*512];                   \
}

template<int PASS>
__global__ __launch_bounds__(256, 2) void kgemm(const u16* __restrict__ hsbF,
                                                const u16* __restrict__ wbF,
                                                const float* __restrict__ bpred,
                                                const float* __restrict__ lse,
                                                float* __restrict__ psum,
                                                float* __restrict__ out){
    int tid = threadIdx.x;
    int bid = blockIdx.x;
    int rg = bid / 50;                    // row group 0..31
    int cg = bid % 50;                    // col group 0..49 (10 chunks each)
    int wid = tid >> 6, lane = tid & 63;
    int l15 = lane & 15, l4 = lane >> 4;
    int rbA = rg*4 + wid;                 // this wave's 64-row block (distinct)
    const float L2E = 1.44269504f;

    // A fragments: loaded ONCE (64 VGPR), zero wave redundancy.
    bf16x8 af[4][4];
    {
        const u16* pa = hsbF + (size_t)rbA*8192 + lane*8;
        #pragma unroll
        for (int q = 0; q < 4; ++q)
            #pragma unroll
            for (int kk = 0; kk < 4; ++kk)
                af[q][kk] = *(const bf16x8*)&pa[(kk*4 + q)*512];
    }
    // lse for this wave's rows (pass 1 only), loaded once.
    float lw[4];
    if (PASS == 1){
        #pragma unroll
        for (int q = 0; q < 4; ++q)
            lw[q] = lse[rbA*64 + q*16 + l15];
    }

    bf16x8 bfr[4][4];
    LOAD_B(cg*10);
    for (int i = 0; i < 10; ++i){
        int ch = cg*10 + i;
        int n0 = ch*64;
        float4 bp4[4];
        #pragma unroll
        for (int f = 0; f < 4; ++f){
            bp4[f] = *(const float4*)&bpred[n0 + f*16 + l4*4];
            if (PASS == 0){
                bp4[f].x *= L2E; bp4[f].y *= L2E; bp4[f].z *= L2E; bp4[f].w *= L2E;
            }
        }
        f32x4 acc[4][4];
        #pragma unroll
        for (int q = 0; q < 4; ++q)
            #pragma unroll
            for (int f = 0; f < 4; ++f)
                acc[q][f] = (f32x4){0.f,0.f,0.f,0.f};
        #pragma unroll
        for (int f = 0; f < 4; ++f)
            #pragma unroll
            for (int q = 0; q < 4; ++q)
                #pragma unroll
                for (int kk = 0; kk < 4; ++kk)
                    acc[q][f] = __builtin_amdgcn_mfma_f32_16x16x32_bf16(
                        bfr[f][kk], af[q][kk], acc[q][f], 0, 0, 0);

        // bfr dead — stream next chunk's B; epilogue hides the latency.
        if (i + 1 < 10) LOAD_B(ch + 1);

        if (PASS == 0){
            float lsum[4];
            #pragma unroll
            for (int q = 0; q < 4; ++q){
                float s = 0.f;
                #pragma unroll
                for (int f = 0; f < 4; ++f)
                    #pragma unroll
                    for (int rr = 0; rr < 4; ++rr){
                        float tt = fmaf(acc[q][f][rr], L2E, bp4[f][rr]);
                        float e; asm("v_exp_f32 %0, %1" : "=v"(e) : "v"(tt));
                        s += e;
                    }
                s += __shfl_xor(s, 16);
                s += __shfl_xor(s, 32);
                lsum[q] = s;
            }
            float sv = (l4 == 0) ? lsum[0] : (l4 == 1) ? lsum[1]
                     : (l4 == 2) ? lsum[2] : lsum[3];
            psum[(size_t)ch*NR + rbA*64 + lane] = sv;
        } else {
            #pragma unroll
            for (int q = 0; q < 4; ++q){
                int grow = rbA*64 + q*16 + l15;
                float* orow = out + (size_t)grow*NV + n0 + l4*4;
                #pragma unroll
                for (int f = 0; f < 4; ++f){
                    f32x4 v;
                    v[0] = acc[q][f][0] + bp4[f].x - lw[q];
                    v[1] = acc[q][f][1] + bp4[f].y - lw[q];
                    v[2] = acc[q][f][2] + bp4[f].z - lw[q];
                    v[3] = acc[q][f][3] + bp4[f].w - lw[q];
                    *(f32x4*)&orow[f*16] = v;
                }
            }
        }
    }
}

// lse[row] = log( sum over 500 chunk partial sums ).  256 blocks x 32 rows.
__global__ __launch_bounds__(256) void klse(const float* __restrict__ psum,
                                            float* __restrict__ lse){
    __shared__ float red[32][8];
    int t = threadIdx.x;
    int row = blockIdx.x*32 + (t >> 3);   // 0..8191
    int grp = t & 7;
    float S = 0.f;
    for (int cc = grp; cc < NCHUNK; cc += 8)
        S += psum[(size_t)cc*NR + row];
    red[t >> 3][grp] = S;
    __syncthreads();
    if (grp == 0){
        float s2 = 0.f;
        #pragma unroll
        for (int g = 0; g < 8; ++g) s2 += red[t >> 3][g];
        lse[row] = __logf(s2);
    }
}

extern "C" void kernel_launch(void* const* d_in, const int* in_sizes, int n_in,
                              void* d_out, int out_size, void* d_ws, size_t ws_size,
                              hipStream_t stream){
    (void)in_sizes; (void)n_in; (void)out_size; (void)ws_size;
    const int*   seq    = (const int*)d_in[0];
    // d_in[1] encoder_output: unused by the reference
    const float* h0     = (const float*)d_in[2];
    const float* c0     = (const float*)d_in[3];
    const float* emb    = (const float*)d_in[4];
    const float* W_ih   = (const float*)d_in[5];
    const float* b_ih   = (const float*)d_in[6];
    const float* W_hh   = (const float*)d_in[7];
    const float* b_hh   = (const float*)d_in[8];
    const float* W_pred = (const float*)d_in[9];
    const float* b_pred = (const float*)d_in[10];
    float* out = (float*)d_out;

    // Workspace layout. psum (16,384,000 B) ALIASES xg (dead after klstm).
    char* ws = (char*)d_ws;
    float* xg   = (float*)(ws);               // 16,777,216 B  [0 .. 16.78M)
    float* psum = (float*)(ws);               // 16,384,000 B  (alias xg)
    float* hh   = (float*)(ws + 16777216);    //     65,536 B
    u16*   hsb  = (u16*)  (ws + 16842752);    //  2,097,152 B  (row-major)
    u16*   wbbF = (u16*)  (ws + 18939904);    //  8,192,000 B  (F layout)
    float* lse  = (float*)(ws + 27131904);    //     32,768 B
    u16*   hsbF = (u16*)  (ws + 27164672);    //  2,097,152 B  (F layout)

    khh<<<64, 256, 0, stream>>>(h0, W_hh, b_ih, b_hh, hh);
    kwb<<<2000, 256, 0, stream>>>(W_pred, wbbF);
    kxg<<<256, 256, 0, stream>>>(seq, emb, W_ih, xg);
    klstm<<<32, 512, 0, stream>>>(xg, hh, W_ih, c0, hsb);
    ktr<<<1024, 256, 0, stream>>>(hsb, hsbF);
    kgemm<0><<<1600, 256, 0, stream>>>(hsbF, wbbF, b_pred, nullptr, psum, out);
    klse<<<256, 256, 0, stream>>>(psum, lse);
    kgemm<1><<<1600, 256, 0, stream>>>(hsbF, wbbF, b_pred, lse, psum, out);
}

// Round 20
// 576.180 us; speedup vs baseline: 1.0113x; 1.0113x over previous
//
#include <hip/hip_runtime.h>

typedef short bf16x8 __attribute__((ext_vector_type(8)));
typedef float f32x4  __attribute__((ext_vector_type(4)));
typedef unsigned short u16;
typedef unsigned short u16x8 __attribute__((ext_vector_type(8)));

#define NB   32
#define NS   256
#define NV   32000
#define NE   128
#define NH   128
#define NR   8192   // NB*NS
#define NG   512    // 4*NH
#define NCHUNK 500  // 250 col chunks x 2 wave halves

__device__ __forceinline__ float sigm(float x){
    return __builtin_amdgcn_rcpf(1.0f + __expf(-x));
}
__device__ __forceinline__ float tanh_fast(float x){
    return 1.0f - 2.0f*__builtin_amdgcn_rcpf(1.0f + __expf(2.0f*x));
}

__device__ __forceinline__ u16 f2bf(float x){
    unsigned u = __float_as_uint(x);
    unsigned r = (u + 0x7FFFu + ((u >> 16) & 1u)) >> 16;
    return (u16)r;
}

// raw barrier: waits only LDS ops, lets global loads/stores stay in flight
__device__ __forceinline__ void lds_barrier(){
    asm volatile("s_waitcnt lgkmcnt(0)" ::: "memory");
    __builtin_amdgcn_s_barrier();
    __builtin_amdgcn_sched_barrier(0);
}

// ---------------------------------------------------------------------------
// Fragment-major (F) layout for a [R][128] bf16 matrix, shared by A and B:
//   row m = rb*64 + q*16 + l15,  col j = kk*32 + l4*8 + e,  lane = l4*16+l15
//   F-addr = rb*8192 + (kk*4+q)*512 + lane*8 + e      (u16 units)
// ---------------------------------------------------------------------------

// hh[b][j] = b_ih[j] + b_hh[j] + dot(h0[b,:], W_hh[j,:])
__global__ __launch_bounds__(256) void khh(const float* __restrict__ h0,
                                           const float* __restrict__ W_hh,
                                           const float* __restrict__ b_ih,
                                           const float* __restrict__ b_hh,
                                           float* __restrict__ hh){
    int idx = blockIdx.x*256 + threadIdx.x;      // 0..16383
    int b = idx >> 9, j = idx & 511;
    const float4* h4 = (const float4*)(h0 + b*NH);
    const float4* w4 = (const float4*)(W_hh + j*NH);
    float acc = b_ih[j] + b_hh[j];
    #pragma unroll
    for (int k = 0; k < 32; ++k){
        float4 a = h4[k], w = w4[k];
        acc += a.x*w.x + a.y*w.y + a.z*w.z + a.w*w.w;
    }
    hh[idx] = acc;
}

// W_pred fp32 -> bf16, written directly in F layout
__global__ __launch_bounds__(256) void kwb(const float* __restrict__ src, u16* __restrict__ dst){
    int a8 = blockIdx.x*256 + threadIdx.x;    // 512000 16B-chunks
    int a = a8 * 8;
    int rb = a >> 13; int blk = (a >> 9) & 15; int lane = (a >> 3) & 63;
    int q = blk & 3, kk = blk >> 2;
    int l15 = lane & 15, l4 = lane >> 4;
    int m = rb*64 + q*16 + l15;
    int j = kk*32 + l4*8;
    const float* s = src + (size_t)m*NH + j;
    float4 x = *(const float4*)s, y = *(const float4*)(s + 4);
    u16x8 o;
    o[0]=f2bf(x.x); o[1]=f2bf(x.y); o[2]=f2bf(x.z); o[3]=f2bf(x.w);
    o[4]=f2bf(y.x); o[5]=f2bf(y.y); o[6]=f2bf(y.z); o[7]=f2bf(y.w);
    *(u16x8*)&dst[a] = o;
}

// hsb (row-major [8192][128] bf16) -> hsbF (F layout). 2 MB, L2-resident.
__global__ __launch_bounds__(256) void ktr(const u16* __restrict__ src, u16* __restrict__ dst){
    int a8 = blockIdx.x*256 + threadIdx.x;    // 262144 16B-chunks
    int a = a8 * 8;
    int rb = a >> 13; int blk = (a >> 9) & 15; int lane = (a >> 3) & 63;
    int q = blk & 3, kk = blk >> 2;
    int l15 = lane & 15, l4 = lane >> 4;
    int m = rb*64 + q*16 + l15;
    int j = kk*32 + l4*8;
    *(uint4*)&dst[a] = *(const uint4*)&src[(size_t)m*NH + j];
}

// xg[r][j] = dot(emb[seq[r]], W_ih[j][0:128]);  32 rows x 512 cols per block
// (32 rows halves the W_ih refetch vs 16: 268 MB -> 134 MB)
__global__ __launch_bounds__(256) void kxg(const int* __restrict__ seq,
                                           const float* __restrict__ emb,
                                           const float* __restrict__ W_ih,
                                           float* __restrict__ xg){
    __shared__ float4 xs[32][32];
    int m0 = blockIdx.x * 32;
    int t = threadIdx.x;
    int r = t >> 3, k8 = t & 7;
    int tok = seq[m0 + r];
    #pragma unroll
    for (int j = 0; j < 4; ++j)
        xs[r][k8*4 + j] = *(const float4*)(emb + (size_t)tok*NE + (k8*4 + j)*4);
    __syncthreads();
    int j0 = t, j1 = t + 256;
    const float4* w0 = (const float4*)(W_ih + (size_t)j0*256);
    const float4* w1 = (const float4*)(W_ih + (size_t)j1*256);
    float acc0[32], acc1[32];
    #pragma unroll
    for (int r2 = 0; r2 < 32; ++r2){ acc0[r2]=0.f; acc1[r2]=0.f; }
    #pragma unroll
    for (int k = 0; k < 32; ++k){
        float4 wa = w0[k], wb = w1[k];
        #pragma unroll
        for (int r2 = 0; r2 < 32; ++r2){
            float4 xv = xs[r2][k];
            acc0[r2] += xv.x*wa.x + xv.y*wa.y + xv.z*wa.z + xv.w*wa.w;
            acc1[r2] += xv.x*wb.x + xv.y*wb.y + xv.z*wb.z + xv.w*wb.w;
        }
    }
    #pragma unroll
    for (int r2 = 0; r2 < 32; ++r2){
        xg[(size_t)(m0+r2)*NG + j0] = acc0[r2];
        xg[(size_t)(m0+r2)*NG + j1] = acc1[r2];
    }
}

// ---------------------------------------------------------------------------
// Sequential LSTM v3: 512 threads/block, quarter-split dots (latency-chain
// bound at ~177us; v2/v3 equivalent — kept).
// ---------------------------------------------------------------------------
#define DOT16(ACC, B) {                                                         \
    asm("v_dot2_f32_bf16 %0, %1, %2, %0" : "+v"(ACC) : "v"(hq0.x), "v"(w2[(B)+0])); \
    asm("v_dot2_f32_bf16 %0, %1, %2, %0" : "+v"(ACC) : "v"(hq0.y), "v"(w2[(B)+1])); \
    asm("v_dot2_f32_bf16 %0, %1, %2, %0" : "+v"(ACC) : "v"(hq0.z), "v"(w2[(B)+2])); \
    asm("v_dot2_f32_bf16 %0, %1, %2, %0" : "+v"(ACC) : "v"(hq0.w), "v"(w2[(B)+3])); \
    asm("v_dot2_f32_bf16 %0, %1, %2, %0" : "+v"(ACC) : "v"(hq1.x), "v"(w2[(B)+4])); \
    asm("v_dot2_f32_bf16 %0, %1, %2, %0" : "+v"(ACC) : "v"(hq1.y), "v"(w2[(B)+5])); \
    asm("v_dot2_f32_bf16 %0, %1, %2, %0" : "+v"(ACC) : "v"(hq1.z), "v"(w2[(B)+6])); \
    asm("v_dot2_f32_bf16 %0, %1, %2, %0" : "+v"(ACC) : "v"(hq1.w), "v"(w2[(B)+7])); \
    asm("v_dot2_f32_bf16 %0, %1, %2, %0" : "+v"(ACC) : "v"(hq2.x), "v"(w2[(B)+8])); \
    asm("v_dot2_f32_bf16 %0, %1, %2, %0" : "+v"(ACC) : "v"(hq2.y), "v"(w2[(B)+9])); \
    asm("v_dot2_f32_bf16 %0, %1, %2, %0" : "+v"(ACC) : "v"(hq2.z), "v"(w2[(B)+10])); \
    asm("v_dot2_f32_bf16 %0, %1, %2, %0" : "+v"(ACC) : "v"(hq2.w), "v"(w2[(B)+11])); \
    asm("v_dot2_f32_bf16 %0, %1, %2, %0" : "+v"(ACC) : "v"(hq3.x), "v"(w2[(B)+12])); \
    asm("v_dot2_f32_bf16 %0, %1, %2, %0" : "+v"(ACC) : "v"(hq3.y), "v"(w2[(B)+13])); \
    asm("v_dot2_f32_bf16 %0, %1, %2, %0" : "+v"(ACC) : "v"(hq3.z), "v"(w2[(B)+14])); \
    asm("v_dot2_f32_bf16 %0, %1, %2, %0" : "+v"(ACC) : "v"(hq3.w), "v"(w2[(B)+15])); \
}

#define LSTM_STEP(S, XV) {                                                      \
    const uint4* h4 = (const uint4*)&hsh2[(S) & 1][0];                          \
    uint4 hq0 = h4[p4+0], hq1 = h4[p4+1], hq2 = h4[p4+2], hq3 = h4[p4+3];       \
    float s0=0.f, s1=0.f, s2=0.f, s3=0.f;                                       \
    DOT16(s0, 0); DOT16(s1, 16); DOT16(s2, 32); DOT16(s3, 48);                  \
    float hbx = hba + (XV);                                                     \
    s0 += (p == 0) ? hbx : 0.f;                                                 \
    s1 += (p == 1) ? hbx : 0.f;                                                 \
    s2 += (p == 2) ? hbx : 0.f;                                                 \
    s3 += (p == 3) ? hbx : 0.f;                                                 \
    s0 += __shfl_xor(s0, 1); s0 += __shfl_xor(s0, 2);                           \
    s1 += __shfl_xor(s1, 1); s1 += __shfl_xor(s1, 2);                           \
    s2 += __shfl_xor(s2, 1); s2 += __shfl_xor(s2, 2);                           \
    s3 += __shfl_xor(s3, 1); s3 += __shfl_xor(s3, 2);                           \
    float cc = sigm(s1)*c0r + sigm(s0)*tanh_fast(s2);                           \
    float h  = sigm(s3)*tanh_fast(cc);                                          \
    u16 hb16 = f2bf(h);                                                         \
    unsigned hp = __shfl_xor((unsigned)hb16, 4);   /* h of row r^1 */           \
    if ((t & 7) == 0){                                                          \
        unsigned pair = (hp << 16) | (unsigned)hb16;                            \
        hsh2[((S) & 1) ^ 1][r >> 1] = pair;                                     \
        *(unsigned*)&hrow[(S)*NH + r] = pair;                                   \
    }                                                                           \
    lds_barrier();                                                              \
}

__global__ __launch_bounds__(512, 1) void klstm(const float* __restrict__ xg,
                                                const float* __restrict__ hh,
                                                const float* __restrict__ W_ih,
                                                const float* __restrict__ c0,
                                                u16* __restrict__ hs){
    __shared__ __align__(16) unsigned hsh2[2][64];   // h as 64 packed bf16 pairs, x2 buffers
    int b = blockIdx.x, t = threadIdx.x;
    int r = t >> 2;          // hidden row 0..127
    int p = t & 3;           // h-quarter == owned gate type (0=i,1=f,2=g,3=o)
    int p4 = p * 4;
    unsigned w2[64];
    #pragma unroll
    for (int j = 0; j < 4; ++j){
        const float2* wrj = (const float2*)(W_ih + (size_t)(j*NH + r)*256 + 128 + p*32);
        #pragma unroll
        for (int k = 0; k < 16; ++k){
            float2 v = wrj[k];
            w2[j*16 + k] = ((unsigned)f2bf(v.y) << 16) | (unsigned)f2bf(v.x);
        }
    }
    float hba = hh[b*NG + p*NH + r];     // bias+enc term for own gate
    float c0r = c0[b*NH + r];
    if (t < 64){ hsh2[0][t] = 0u; }      // h_init = 0
    __syncthreads();
    const float* xrow = xg + (size_t)b*NS*NG + p*NH + r;   // own gate's x, stride NG
    u16* hrow = hs + (size_t)b*NS*NH;
    float xv0 = xrow[0], xv1 = xrow[NG], xv2 = xrow[2*NG], xv3 = xrow[3*NG];
    for (int s4 = 0; s4 < NS; s4 += 4){
        float n0=0.f, n1=0.f, n2=0.f, n3=0.f;
        if (s4 + 4 < NS){
            const float* xn = xrow + (size_t)(s4+4)*NG;
            n0 = xn[0]; n1 = xn[NG]; n2 = xn[2*NG]; n3 = xn[3*NG];
        }
        LSTM_STEP(s4+0, xv0);
        LSTM_STEP(s4+1, xv1);
        LSTM_STEP(s4+2, xv2);
        LSTM_STEP(s4+3, xv3);
        xv0=n0; xv1=n1; xv2=n2; xv3=n3;
    }
}

// ---------------------------------------------------------------------------
// Barrier-free, LDS-free MFMA GEMM — R16 dataflow (proven best 549.7us):
// stream A (2 MB, L2-resident -> redundant reads are L2 hits), persist B in
// regs per wave. Coalesced F-layout loads; af reloaded for r+1 between MFMA
// and epilogue (epilogue hides L2 latency).
// PASS 0: psum[(c*2+wc)][row] = sum_j exp(logit).  PASS 1: out = logit - lse.
// ---------------------------------------------------------------------------

#define LOAD_A(DST, R) {                                                        \
    int rbA = (mbase >> 6) + (R)*2 + wr;                                        \
    const u16* pa = hsbF + (size_t)rbA*8192 + lane*8;                           \
    _Pragma("unroll")                                                           \
    for (int q = 0; q < 4; ++q)                                                 \
        _Pragma("unroll")                                                       \
        for (int kk = 0; kk < 4; ++kk)                                          \
            DST[q][kk] = *(const bf16x8*)&pa[(kk*4 + q)*512];                   \
}

template<int PASS>
__global__ __launch_bounds__(256, 2) void kgemm(const u16* __restrict__ hsbF,
                                                const u16* __restrict__ wbF,
                                                const float* __restrict__ bpred,
                                                const float* __restrict__ lse,
                                                float* __restrict__ psum,
                                                float* __restrict__ out){
    int tid = threadIdx.x;
    int bid = blockIdx.x;
    int c    = bid >> 1;                  // col chunk 0..249
    int half = bid & 1;                   // row half
    int n0 = c * 128;
    int mbase = half * 4096;

    int wid = tid >> 6, lane = tid & 63;
    int wr = wid >> 1, wc = wid & 1;      // 2 row-groups x 2 col-groups of 64
    int l15 = lane & 15, l4 = lane >> 4;
    const float L2E = 1.44269504f;
    float4 bp4[4];                        // pass1: bias; pass0: bias*log2e
    #pragma unroll
    for (int f = 0; f < 4; ++f){
        bp4[f] = *(const float4*)&bpred[n0 + wc*64 + f*16 + l4*4];
        if (PASS == 0){
            bp4[f].x *= L2E; bp4[f].y *= L2E; bp4[f].z *= L2E; bp4[f].w *= L2E;
        }
    }

    // B fragments: this wave's 64x128 W chunk, in regs, coalesced F reads.
    bf16x8 bfr[4][4];
    {
        int rbB = c*2 + wc;
        const u16* pb = wbF + (size_t)rbB*8192 + lane*8;
        #pragma unroll
        for (int f = 0; f < 4; ++f)
            #pragma unroll
            for (int kk = 0; kk < 4; ++kk)
                bfr[f][kk] = *(const bf16x8*)&pb[(kk*4 + f)*512];
    }

    bf16x8 af[4][4];
    LOAD_A(af, 0);
    for (int r = 0; r < 32; ++r){
        f32x4 acc[4][4];
        #pragma unroll
        for (int q = 0; q < 4; ++q)
            #pragma unroll
            for (int f = 0; f < 4; ++f)
                acc[q][f] = (f32x4){0.f,0.f,0.f,0.f};
        #pragma unroll
        for (int f = 0; f < 4; ++f)
            #pragma unroll
            for (int q = 0; q < 4; ++q)
                #pragma unroll
                for (int kk = 0; kk < 4; ++kk)
                    acc[q][f] = __builtin_amdgcn_mfma_f32_16x16x32_bf16(
                        bfr[f][kk], af[q][kk], acc[q][f], 0, 0, 0);

        // af is dead now — reload same regs for r+1; epilogue hides latency.
        if (r + 1 < 32) LOAD_A(af, r+1);

        if (PASS == 0){
            float lsum[4];
            #pragma unroll
            for (int q = 0; q < 4; ++q){
                float s = 0.f;
                #pragma unroll
                for (int f = 0; f < 4; ++f)
                    #pragma unroll
                    for (int rr = 0; rr < 4; ++rr){
                        float tt = fmaf(acc[q][f][rr], L2E, bp4[f][rr]);
                        float e; asm("v_exp_f32 %0, %1" : "=v"(e) : "v"(tt));
                        s += e;
                    }
                s += __shfl_xor(s, 16);
                s += __shfl_xor(s, 32);
                lsum[q] = s;
            }
            float sv = (l4 == 0) ? lsum[0] : (l4 == 1) ? lsum[1]
                     : (l4 == 2) ? lsum[2] : lsum[3];
            psum[(size_t)(c*2 + wc)*NR + mbase + r*128 + wr*64 + lane] = sv;
        } else {
            #pragma unroll
            for (int q = 0; q < 4; ++q){
                int grow = mbase + r*128 + wr*64 + q*16 + l15;
                float lw = lse[grow];
                float* orow = out + (size_t)grow*NV + n0 + wc*64 + l4*4;
                #pragma unroll
                for (int f = 0; f < 4; ++f){
                    f32x4 v;
                    v[0] = acc[q][f][0] + bp4[f].x - lw;
                    v[1] = acc[q][f][1] + bp4[f].y - lw;
                    v[2] = acc[q][f][2] + bp4[f].z - lw;
                    v[3] = acc[q][f][3] + bp4[f].w - lw;
                    *(f32x4*)&orow[f*16] = v;
                }
            }
        }
    }
}

// lse[row] = log( sum over 500 partial-chunk sums ).  256 blocks x 32 rows.
__global__ __launch_bounds__(256) void klse(const float* __restrict__ psum,
                                            float* __restrict__ lse){
    __shared__ float red[32][8];
    int t = threadIdx.x;
    int row = blockIdx.x*32 + (t >> 3);   // 0..8191
    int grp = t & 7;
    float S = 0.f;
    for (int cc = grp; cc < NCHUNK; cc += 8)
        S += psum[(size_t)cc*NR + row];
    red[t >> 3][grp] = S;
    __syncthreads();
    if (grp == 0){
        float s2 = 0.f;
        #pragma unroll
        for (int g = 0; g < 8; ++g) s2 += red[t >> 3][g];
        lse[row] = __logf(s2);
    }
}

extern "C" void kernel_launch(void* const* d_in, const int* in_sizes, int n_in,
                              void* d_out, int out_size, void* d_ws, size_t ws_size,
                              hipStream_t stream){
    (void)in_sizes; (void)n_in; (void)out_size; (void)ws_size;
    const int*   seq    = (const int*)d_in[0];
    // d_in[1] encoder_output: unused by the reference
    const float* h0     = (const float*)d_in[2];
    const float* c0     = (const float*)d_in[3];
    const float* emb    = (const float*)d_in[4];
    const float* W_ih   = (const float*)d_in[5];
    const float* b_ih   = (const float*)d_in[6];
    const float* W_hh   = (const float*)d_in[7];
    const float* b_hh   = (const float*)d_in[8];
    const float* W_pred = (const float*)d_in[9];
    const float* b_pred = (const float*)d_in[10];
    float* out = (float*)d_out;

    // Workspace layout. psum (16,384,000 B) ALIASES xg (dead after klstm).
    char* ws = (char*)d_ws;
    float* xg   = (float*)(ws);               // 16,777,216 B  [0 .. 16.78M)
    float* psum = (float*)(ws);               // 16,384,000 B  (alias xg)
    float* hh   = (float*)(ws + 16777216);    //     65,536 B
    u16*   hsb  = (u16*)  (ws + 16842752);    //  2,097,152 B  (row-major)
    u16*   wbbF = (u16*)  (ws + 18939904);    //  8,192,000 B  (F layout)
    float* lse  = (float*)(ws + 27131904);    //     32,768 B
    u16*   hsbF = (u16*)  (ws + 27164672);    //  2,097,152 B  (F layout)

    khh<<<64, 256, 0, stream>>>(h0, W_hh, b_ih, b_hh, hh);
    kwb<<<2000, 256, 0, stream>>>(W_pred, wbbF);
    kxg<<<256, 256, 0, stream>>>(seq, emb, W_ih, xg);
    klstm<<<32, 512, 0, stream>>>(xg, hh, W_ih, c0, hsb);
    ktr<<<1024, 256, 0, stream>>>(hsb, hsbF);
    kgemm<0><<<500, 256, 0, stream>>>(hsbF, wbbF, b_pred, nullptr, psum, out);
    klse<<<256, 256, 0, stream>>>(psum, lse);
    kgemm<1><<<500, 256, 0, stream>>>(hsbF, wbbF, b_pred, lse, psum, out);
}

// Round 21
// 551.669 us; speedup vs baseline: 1.0562x; 1.0444x over previous
//
#include <hip/hip_runtime.h>

typedef short bf16x8 __attribute__((ext_vector_type(8)));
typedef float f32x4  __attribute__((ext_vector_type(4)));
typedef unsigned short u16;
typedef unsigned short u16x8 __attribute__((ext_vector_type(8)));

#define NB   32
#define NS   256
#define NV   32000
#define NE   128
#define NH   128
#define NR   8192   // NB*NS
#define NG   512    // 4*NH
#define NCHUNK 500  // 250 col chunks x 2 wave halves

__device__ __forceinline__ float sigm(float x){
    return __builtin_amdgcn_rcpf(1.0f + __expf(-x));
}
__device__ __forceinline__ float tanh_fast(float x){
    return 1.0f - 2.0f*__builtin_amdgcn_rcpf(1.0f + __expf(2.0f*x));
}

__device__ __forceinline__ u16 f2bf(float x){
    unsigned u = __float_as_uint(x);
    unsigned r = (u + 0x7FFFu + ((u >> 16) & 1u)) >> 16;
    return (u16)r;
}

// raw barrier: waits only LDS ops, lets global loads/stores stay in flight
__device__ __forceinline__ void lds_barrier(){
    asm volatile("s_waitcnt lgkmcnt(0)" ::: "memory");
    __builtin_amdgcn_s_barrier();
    __builtin_amdgcn_sched_barrier(0);
}

// ---------------------------------------------------------------------------
// Fragment-major (F) layout for a [R][128] bf16 matrix, shared by A and B:
//   row m = rb*64 + q*16 + l15,  col j = kk*32 + l4*8 + e,  lane = l4*16+l15
//   F-addr = rb*8192 + (kk*4+q)*512 + lane*8 + e      (u16 units)
// ---------------------------------------------------------------------------

// Fused front-end: khh (bid 0..63) | kwb (64..2063) | kxg (2064..2575).
// All three are mutually independent; one dispatch removes two kernel
// boundaries (full-drain + launch gap each).
__global__ __launch_bounds__(256) void kpre(const float* __restrict__ h0,
                                            const float* __restrict__ W_hh,
                                            const float* __restrict__ b_ih,
                                            const float* __restrict__ b_hh,
                                            float* __restrict__ hh,
                                            const float* __restrict__ Wp,
                                            u16* __restrict__ wbF,
                                            const int* __restrict__ seq,
                                            const float* __restrict__ emb,
                                            const float* __restrict__ W_ih,
                                            float* __restrict__ xg){
    __shared__ float4 xs[16][32];
    int bid = blockIdx.x;
    int t = threadIdx.x;
    if (bid < 64){
        // ---- khh: hh[b][j] = b_ih[j] + b_hh[j] + dot(h0[b,:], W_hh[j,:])
        int idx = bid*256 + t;               // 0..16383
        int b = idx >> 9, j = idx & 511;
        const float4* h4 = (const float4*)(h0 + b*NH);
        const float4* w4 = (const float4*)(W_hh + j*NH);
        float acc = b_ih[j] + b_hh[j];
        #pragma unroll
        for (int k = 0; k < 32; ++k){
            float4 a = h4[k], w = w4[k];
            acc += a.x*w.x + a.y*w.y + a.z*w.z + a.w*w.w;
        }
        hh[idx] = acc;
    } else if (bid < 2064){
        // ---- kwb: W_pred fp32 -> bf16, F layout
        int a8 = (bid - 64)*256 + t;         // 512000 16B-chunks
        int a = a8 * 8;
        int rb = a >> 13; int blk = (a >> 9) & 15; int lane = (a >> 3) & 63;
        int q = blk & 3, kk = blk >> 2;
        int l15 = lane & 15, l4 = lane >> 4;
        int m = rb*64 + q*16 + l15;
        int j = kk*32 + l4*8;
        const float* s = Wp + (size_t)m*NH + j;
        float4 x = *(const float4*)s, y = *(const float4*)(s + 4);
        u16x8 o;
        o[0]=f2bf(x.x); o[1]=f2bf(x.y); o[2]=f2bf(x.z); o[3]=f2bf(x.w);
        o[4]=f2bf(y.x); o[5]=f2bf(y.y); o[6]=f2bf(y.z); o[7]=f2bf(y.w);
        *(u16x8*)&wbF[a] = o;
    } else {
        // ---- kxg: xg[r][j] = dot(emb[seq[r]], W_ih[j][0:128]); 16 rows/block
        int m0 = (bid - 2064) * 16;
        int r = t >> 4, k4 = t & 15;
        int tok = seq[m0 + r];
        xs[r][k4]      = *(const float4*)(emb + (size_t)tok*NE + k4*4);
        xs[r][k4 + 16] = *(const float4*)(emb + (size_t)tok*NE + (k4+16)*4);
        __syncthreads();
        int j0 = t, j1 = t + 256;
        const float4* w0 = (const float4*)(W_ih + (size_t)j0*256);
        const float4* w1 = (const float4*)(W_ih + (size_t)j1*256);
        float acc0[16], acc1[16];
        #pragma unroll
        for (int r2 = 0; r2 < 16; ++r2){ acc0[r2]=0.f; acc1[r2]=0.f; }
        #pragma unroll
        for (int k = 0; k < 32; ++k){
            float4 wa = w0[k], wb = w1[k];
            #pragma unroll
            for (int r2 = 0; r2 < 16; ++r2){
                float4 xv = xs[r2][k];
                acc0[r2] += xv.x*wa.x + xv.y*wa.y + xv.z*wa.z + xv.w*wa.w;
                acc1[r2] += xv.x*wb.x + xv.y*wb.y + xv.z*wb.z + xv.w*wb.w;
            }
        }
        #pragma unroll
        for (int r2 = 0; r2 < 16; ++r2){
            xg[(size_t)(m0+r2)*NG + j0] = acc0[r2];
            xg[(size_t)(m0+r2)*NG + j1] = acc1[r2];
        }
    }
}

// ---------------------------------------------------------------------------
// Sequential LSTM v3: 512 threads/block, quarter-split dots. h row written
// DIRECTLY in F layout (row m = b*256+s, col j = r) -> ktr kernel removed.
// For row m: rb=m>>6, q=(m>>4)&3, l15f=m&15; col r: kk=r>>5, l4f=(r>>3)&3,
// e=r&7. u32 pair (cols r,r+1; r even):
//   off32 = rb*4096 + ((r>>5)*4+q)*256 + (((r>>3)&3)*16 + l15f)*4 + ((r&7)>>1)
// ---------------------------------------------------------------------------
#define DOT16(ACC, B) {                                                         \
    asm("v_dot2_f32_bf16 %0, %1, %2, %0" : "+v"(ACC) : "v"(hq0.x), "v"(w2[(B)+0])); \
    asm("v_dot2_f32_bf16 %0, %1, %2, %0" : "+v"(ACC) : "v"(hq0.y), "v"(w2[(B)+1])); \
    asm("v_dot2_f32_bf16 %0, %1, %2, %0" : "+v"(ACC) : "v"(hq0.z), "v"(w2[(B)+2])); \
    asm("v_dot2_f32_bf16 %0, %1, %2, %0" : "+v"(ACC) : "v"(hq0.w), "v"(w2[(B)+3])); \
    asm("v_dot2_f32_bf16 %0, %1, %2, %0" : "+v"(ACC) : "v"(hq1.x), "v"(w2[(B)+4])); \
    asm("v_dot2_f32_bf16 %0, %1, %2, %0" : "+v"(ACC) : "v"(hq1.y), "v"(w2[(B)+5])); \
    asm("v_dot2_f32_bf16 %0, %1, %2, %0" : "+v"(ACC) : "v"(hq1.z), "v"(w2[(B)+6])); \
    asm("v_dot2_f32_bf16 %0, %1, %2, %0" : "+v"(ACC) : "v"(hq1.w), "v"(w2[(B)+7])); \
    asm("v_dot2_f32_bf16 %0, %1, %2, %0" : "+v"(ACC) : "v"(hq2.x), "v"(w2[(B)+8])); \
    asm("v_dot2_f32_bf16 %0, %1, %2, %0" : "+v"(ACC) : "v"(hq2.y), "v"(w2[(B)+9])); \
    asm("v_dot2_f32_bf16 %0, %1, %2, %0" : "+v"(ACC) : "v"(hq2.z), "v"(w2[(B)+10])); \
    asm("v_dot2_f32_bf16 %0, %1, %2, %0" : "+v"(ACC) : "v"(hq2.w), "v"(w2[(B)+11])); \
    asm("v_dot2_f32_bf16 %0, %1, %2, %0" : "+v"(ACC) : "v"(hq3.x), "v"(w2[(B)+12])); \
    asm("v_dot2_f32_bf16 %0, %1, %2, %0" : "+v"(ACC) : "v"(hq3.y), "v"(w2[(B)+13])); \
    asm("v_dot2_f32_bf16 %0, %1, %2, %0" : "+v"(ACC) : "v"(hq3.z), "v"(w2[(B)+14])); \
    asm("v_dot2_f32_bf16 %0, %1, %2, %0" : "+v"(ACC) : "v"(hq3.w), "v"(w2[(B)+15])); \
}

#define LSTM_STEP(S, XV) {                                                      \
    const uint4* h4 = (const uint4*)&hsh2[(S) & 1][0];                          \
    uint4 hq0 = h4[p4+0], hq1 = h4[p4+1], hq2 = h4[p4+2], hq3 = h4[p4+3];       \
    float s0=0.f, s1=0.f, s2=0.f, s3=0.f;                                       \
    DOT16(s0, 0); DOT16(s1, 16); DOT16(s2, 32); DOT16(s3, 48);                  \
    float hbx = hba + (XV);                                                     \
    s0 += (p == 0) ? hbx : 0.f;                                                 \
    s1 += (p == 1) ? hbx : 0.f;                                                 \
    s2 += (p == 2) ? hbx : 0.f;                                                 \
    s3 += (p == 3) ? hbx : 0.f;                                                 \
    s0 += __shfl_xor(s0, 1); s0 += __shfl_xor(s0, 2);                           \
    s1 += __shfl_xor(s1, 1); s1 += __shfl_xor(s1, 2);                           \
    s2 += __shfl_xor(s2, 1); s2 += __shfl_xor(s2, 2);                           \
    s3 += __shfl_xor(s3, 1); s3 += __shfl_xor(s3, 2);                           \
    float cc = sigm(s1)*c0r + sigm(s0)*tanh_fast(s2);                           \
    float h  = sigm(s3)*tanh_fast(cc);                                          \
    u16 hb16 = f2bf(h);                                                         \
    unsigned hp = __shfl_xor((unsigned)hb16, 4);   /* h of row r^1 */           \
    if ((t & 7) == 0){                                                          \
        unsigned pair = (hp << 16) | (unsigned)hb16;                            \
        hsh2[((S) & 1) ^ 1][r >> 1] = pair;                                     \
        int m  = bm + (S);                                                      \
        int off32 = (m >> 6)*4096 + ((r >> 5)*4 + ((m >> 4) & 3))*256           \
                  + ((((r >> 3) & 3)*16) + (m & 15))*4 + ((r & 7) >> 1);        \
        ((unsigned*)hsF)[off32] = pair;                                         \
    }                                                                           \
    lds_barrier();                                                              \
}

__global__ __launch_bounds__(512, 1) void klstm(const float* __restrict__ xg,
                                                const float* __restrict__ hh,
                                                const float* __restrict__ W_ih,
                                                const float* __restrict__ c0,
                                                u16* __restrict__ hsF){
    __shared__ __align__(16) unsigned hsh2[2][64];   // h as 64 packed bf16 pairs, x2 buffers
    int b = blockIdx.x, t = threadIdx.x;
    int r = t >> 2;          // hidden row 0..127
    int p = t & 3;           // h-quarter == owned gate type (0=i,1=f,2=g,3=o)
    int p4 = p * 4;
    int bm = b * NS;         // global row base for this batch
    unsigned w2[64];
    #pragma unroll
    for (int j = 0; j < 4; ++j){
        const float2* wrj = (const float2*)(W_ih + (size_t)(j*NH + r)*256 + 128 + p*32);
        #pragma unroll
        for (int k = 0; k < 16; ++k){
            float2 v = wrj[k];
            w2[j*16 + k] = ((unsigned)f2bf(v.y) << 16) | (unsigned)f2bf(v.x);
        }
    }
    float hba = hh[b*NG + p*NH + r];     // bias+enc term for own gate
    float c0r = c0[b*NH + r];
    if (t < 64){ hsh2[0][t] = 0u; }      // h_init = 0
    __syncthreads();
    const float* xrow = xg + (size_t)b*NS*NG + p*NH + r;   // own gate's x, stride NG
    float xv0 = xrow[0], xv1 = xrow[NG], xv2 = xrow[2*NG], xv3 = xrow[3*NG];
    for (int s4 = 0; s4 < NS; s4 += 4){
        float n0=0.f, n1=0.f, n2=0.f, n3=0.f;
        if (s4 + 4 < NS){
            const float* xn = xrow + (size_t)(s4+4)*NG;
            n0 = xn[0]; n1 = xn[NG]; n2 = xn[2*NG]; n3 = xn[3*NG];
        }
        LSTM_STEP(s4+0, xv0);
        LSTM_STEP(s4+1, xv1);
        LSTM_STEP(s4+2, xv2);
        LSTM_STEP(s4+3, xv3);
        xv0=n0; xv1=n1; xv2=n2; xv3=n3;
    }
}

// ---------------------------------------------------------------------------
// Barrier-free, LDS-free MFMA GEMM — R16 dataflow (proven best):
// stream A (2 MB, L2-resident), persist B in regs per wave. Coalesced
// F-layout loads; af reloaded for r+1 between MFMA and epilogue.
// PASS 0: psum[(c*2+wc)][row] = sum_j exp(logit).  PASS 1: out = logit - lse.
// ---------------------------------------------------------------------------

#define LOAD_A(DST, R) {                                                        \
    int rbA = (mbase >> 6) + (R)*2 + wr;                                        \
    const u16* pa = hsbF + (size_t)rbA*8192 + lane*8;                           \
    _Pragma("unroll")                                                           \
    for (int q = 0; q < 4; ++q)                                                 \
        _Pragma("unroll")                                                       \
        for (int kk = 0; kk < 4; ++kk)                                          \
            DST[q][kk] = *(const bf16x8*)&pa[(kk*4 + q)*512];                   \
}

template<int PASS>
__global__ __launch_bounds__(256, 2) void kgemm(const u16* __restrict__ hsbF,
                                                const u16* __restrict__ wbF,
                                                const float* __restrict__ bpred,
                                                const float* __restrict__ lse,
                                                float* __restrict__ psum,
                                                float* __restrict__ out){
    int tid = threadIdx.x;
    int bid = blockIdx.x;
    int c    = bid >> 1;                  // col chunk 0..249
    int half = bid & 1;                   // row half
    int n0 = c * 128;
    int mbase = half * 4096;

    int wid = tid >> 6, lane = tid & 63;
    int wr = wid >> 1, wc = wid & 1;      // 2 row-groups x 2 col-groups of 64
    int l15 = lane & 15, l4 = lane >> 4;
    const float L2E = 1.44269504f;
    float4 bp4[4];                        // pass1: bias; pass0: bias*log2e
    #pragma unroll
    for (int f = 0; f < 4; ++f){
        bp4[f] = *(const float4*)&bpred[n0 + wc*64 + f*16 + l4*4];
        if (PASS == 0){
            bp4[f].x *= L2E; bp4[f].y *= L2E; bp4[f].z *= L2E; bp4[f].w *= L2E;
        }
    }

    // B fragments: this wave's 64x128 W chunk, in regs, coalesced F reads.
    bf16x8 bfr[4][4];
    {
        int rbB = c*2 + wc;
        const u16* pb = wbF + (size_t)rbB*8192 + lane*8;
        #pragma unroll
        for (int f = 0; f < 4; ++f)
            #pragma unroll
            for (int kk = 0; kk < 4; ++kk)
                bfr[f][kk] = *(const bf16x8*)&pb[(kk*4 + f)*512];
    }

    bf16x8 af[4][4];
    LOAD_A(af, 0);
    for (int r = 0; r < 32; ++r){
        f32x4 acc[4][4];
        #pragma unroll
        for (int q = 0; q < 4; ++q)
            #pragma unroll
            for (int f = 0; f < 4; ++f)
                acc[q][f] = (f32x4){0.f,0.f,0.f,0.f};
        #pragma unroll
        for (int f = 0; f < 4; ++f)
            #pragma unroll
            for (int q = 0; q < 4; ++q)
                #pragma unroll
                for (int kk = 0; kk < 4; ++kk)
                    acc[q][f] = __builtin_amdgcn_mfma_f32_16x16x32_bf16(
                        bfr[f][kk], af[q][kk], acc[q][f], 0, 0, 0);

        // af is dead now — reload same regs for r+1; epilogue hides latency.
        if (r + 1 < 32) LOAD_A(af, r+1);

        if (PASS == 0){
            float lsum[4];
            #pragma unroll
            for (int q = 0; q < 4; ++q){
                float s = 0.f;
                #pragma unroll
                for (int f = 0; f < 4; ++f)
                    #pragma unroll
                    for (int rr = 0; rr < 4; ++rr){
                        float tt = fmaf(acc[q][f][rr], L2E, bp4[f][rr]);
                        float e; asm("v_exp_f32 %0, %1" : "=v"(e) : "v"(tt));
                        s += e;
                    }
                s += __shfl_xor(s, 16);
                s += __shfl_xor(s, 32);
                lsum[q] = s;
            }
            float sv = (l4 == 0) ? lsum[0] : (l4 == 1) ? lsum[1]
                     : (l4 == 2) ? lsum[2] : lsum[3];
            psum[(size_t)(c*2 + wc)*NR + mbase + r*128 + wr*64 + lane] = sv;
        } else {
            #pragma unroll
            for (int q = 0; q < 4; ++q){
                int grow = mbase + r*128 + wr*64 + q*16 + l15;
                float lw = lse[grow];
                float* orow = out + (size_t)grow*NV + n0 + wc*64 + l4*4;
                #pragma unroll
                for (int f = 0; f < 4; ++f){
                    f32x4 v;
                    v[0] = acc[q][f][0] + bp4[f].x - lw;
                    v[1] = acc[q][f][1] + bp4[f].y - lw;
                    v[2] = acc[q][f][2] + bp4[f].z - lw;
                    v[3] = acc[q][f][3] + bp4[f].w - lw;
                    *(f32x4*)&orow[f*16] = v;
                }
            }
        }
    }
}

// lse[row] = log( sum over 500 partial-chunk sums ).  256 blocks x 32 rows.
__global__ __launch_bounds__(256) void klse(const float* __restrict__ psum,
                                            float* __restrict__ lse){
    __shared__ float red[32][8];
    int t = threadIdx.x;
    int row = blockIdx.x*32 + (t >> 3);   // 0..8191
    int grp = t & 7;
    float S = 0.f;
    for (int cc = grp; cc < NCHUNK; cc += 8)
        S += psum[(size_t)cc*NR + row];
    red[t >> 3][grp] = S;
    __syncthreads();
    if (grp == 0){
        float s2 = 0.f;
        #pragma unroll
        for (int g = 0; g < 8; ++g) s2 += red[t >> 3][g];
        lse[row] = __logf(s2);
    }
}

extern "C" void kernel_launch(void* const* d_in, const int* in_sizes, int n_in,
                              void* d_out, int out_size, void* d_ws, size_t ws_size,
                              hipStream_t stream){
    (void)in_sizes; (void)n_in; (void)out_size; (void)ws_size;
    const int*   seq    = (const int*)d_in[0];
    // d_in[1] encoder_output: unused by the reference
    const float* h0     = (const float*)d_in[2];
    const float* c0     = (const float*)d_in[3];
    const float* emb    = (const float*)d_in[4];
    const float* W_ih   = (const float*)d_in[5];
    const float* b_ih   = (const float*)d_in[6];
    const float* W_hh   = (const float*)d_in[7];
    const float* b_hh   = (const float*)d_in[8];
    const float* W_pred = (const float*)d_in[9];
    const float* b_pred = (const float*)d_in[10];
    float* out = (float*)d_out;

    // Workspace layout. psum (16,384,000 B) ALIASES xg (dead after klstm).
    char* ws = (char*)d_ws;
    float* xg   = (float*)(ws);               // 16,777,216 B  [0 .. 16.78M)
    float* psum = (float*)(ws);               // 16,384,000 B  (alias xg)
    float* hh   = (float*)(ws + 16777216);    //     65,536 B
    u16*   wbbF = (u16*)  (ws + 18939904);    //  8,192,000 B  (F layout)
    float* lse  = (float*)(ws + 27131904);    //     32,768 B
    u16*   hsbF = (u16*)  (ws + 27164672);    //  2,097,152 B  (F layout)

    kpre<<<2576, 256, 0, stream>>>(h0, W_hh, b_ih, b_hh, hh,
                                   W_pred, wbbF, seq, emb, W_ih, xg);
    klstm<<<32, 512, 0, stream>>>(xg, hh, W_ih, c0, hsbF);
    kgemm<0><<<500, 256, 0, stream>>>(hsbF, wbbF, b_pred, nullptr, psum, out);
    klse<<<256, 256, 0, stream>>>(psum, lse);
    kgemm<1><<<500, 256, 0, stream>>>(hsbF, wbbF, b_pred, lse, psum, out);
}